// Round 7
// baseline (566.401 us; speedup 1.0000x reference)
//
#include <hip/hip_runtime.h>
#include <hip/hip_bf16.h>

typedef __attribute__((ext_vector_type(8))) short short8;
typedef __attribute__((ext_vector_type(4))) short short4v;
typedef __attribute__((ext_vector_type(4))) float f32x4;

__device__ __forceinline__ short f2bf(float f) {
  union { __hip_bfloat16 h; short s; } u;
  u.h = __float2bfloat16(f);
  return u.s;
}

#define EP_STRIDE 68   // f32; 272 B rows: 16B-aligned b128 reads, +4 bank skew

// One wave computes C[m0..m0+64, n0..n0+64]. No LDS in the main loop.
// All 8 waves of a block share ONE n-tile (same W panel) and cover the 8
// m-groups -> W is HBM-read once per panel, re-reads hit same-CU L1/L2.
// A raw s_barrier every 4 K-steps bounds wave drift (keeps panel L1-hot)
// without any waitcnt drain (no data handoff through memory).
__device__ __forceinline__ void sgemm_wave(
    const short* __restrict__ A,
    const float* __restrict__ W,
    const float* __restrict__ bias,
    float* __restrict__ C,
    int K, int N, int m0, int n0, float* ep)
{
  const int lane = threadIdx.x & 63;
  const int l16  = lane & 15;
  const int lq   = lane >> 4;

  const short* ap = A + (size_t)(m0 + l16) * K + lq * 8;
  const float* wp = W + (size_t)(n0 + l16) * K + lq * 8;
  const size_t KS16 = (size_t)16 * K;

  f32x4 acc[4][4];
  #pragma unroll
  for (int i = 0; i < 4; ++i)
    #pragma unroll
    for (int j = 0; j < 4; ++j) {
      f32x4 z = {0.f, 0.f, 0.f, 0.f};
      acc[i][j] = z;
    }

  const int nsteps = K >> 5;
  for (int s = 0; s < nsteps; ++s) {
    const int k = s << 5;
    short8 a[4];
    #pragma unroll
    for (int mf = 0; mf < 4; ++mf)
      a[mf] = *(const short8*)(ap + KS16 * mf + k);
    #pragma unroll
    for (int nf = 0; nf < 4; ++nf) {
      f32x4 u = *(const f32x4*)(wp + KS16 * nf + k);
      f32x4 v = *(const f32x4*)(wp + KS16 * nf + k + 4);
      short8 b;
      #pragma unroll
      for (int i = 0; i < 4; ++i) { b[i] = f2bf(u[i]); b[i + 4] = f2bf(v[i]); }
      #pragma unroll
      for (int mf = 0; mf < 4; ++mf)
        acc[mf][nf] = __builtin_amdgcn_mfma_f32_16x16x32_bf16(a[mf], b, acc[mf][nf], 0, 0, 0);
    }
    if ((s & 3) == 3) __builtin_amdgcn_s_barrier();   // drift bound, no drain
  }

  // epilogue: per-wave LDS transpose -> full-line f32x4 stores.
  // acc layout: col = nf*16 + l16, row = mf*16 + lq*4 + r  [m89]
  float bvv[4];
  #pragma unroll
  for (int nf = 0; nf < 4; ++nf) bvv[nf] = bias[n0 + nf * 16 + l16];

  const int rr = lq;               // 0..3: which f32x4 chunk of a row
  const int cc = l16 * 4;          // 0..60
  #pragma unroll
  for (int mf = 0; mf < 4; ++mf) {
    #pragma unroll
    for (int nf = 0; nf < 4; ++nf)
      #pragma unroll
      for (int r = 0; r < 4; ++r)
        ep[(lq * 4 + r) * EP_STRIDE + nf * 16 + l16] = acc[mf][nf][r] + bvv[nf];
    // wave-local DS ops in-order; compiler inserts lgkmcnt before reads
    #pragma unroll
    for (int i = 0; i < 4; ++i) {
      f32x4 v = *(const f32x4*)&ep[(i * 4 + rr) * EP_STRIDE + cc];
      *(f32x4*)&C[(size_t)(m0 + mf * 16 + i * 4 + rr) * N + n0 + cc] = v;
    }
  }
}

__global__ __launch_bounds__(512, 4) void gru_gemms_kernel(
    const short* __restrict__ xbf, const short* __restrict__ hbf,
    const float* __restrict__ W_ih, const float* __restrict__ W_hh,
    const float* __restrict__ b_ih, const float* __restrict__ b_hh,
    float* __restrict__ gi, float* __restrict__ gh)
{
  __shared__ float eps[8][16 * EP_STRIDE];
  const int wv = threadIdx.x >> 6;           // m-group 0..7
  const bool second = blockIdx.x >= 96;
  const int nt = second ? (int)blockIdx.x - 96 : (int)blockIdx.x;  // n-tile
  sgemm_wave(second ? hbf : xbf,
             second ? W_hh : W_ih,
             second ? b_hh : b_ih,
             second ? gh : gi,
             second ? 2048 : 1024,
             6144, wv * 64, nt * 64, eps[wv]);
}

__global__ __launch_bounds__(512, 4) void logits_kernel(
    const short* __restrict__ hnbf, const float* __restrict__ fc_W,
    const float* __restrict__ fc_b, float* __restrict__ out)
{
  __shared__ float eps[8][16 * EP_STRIDE];
  const int wv = threadIdx.x >> 6;           // m-group 0..7
  const int nt = (int)blockIdx.x;            // n-tile 0..499 (same for all waves)
  sgemm_wave(hnbf, fc_W, fc_b, out, 2048, 32000, wv * 64, nt * 64, eps[wv]);
}

__global__ void prep_kernel(const int* __restrict__ idx,
                            const float* __restrict__ hid,
                            const float* __restrict__ emb,
                            short* __restrict__ xbf, short* __restrict__ hbf)
{
  int i = blockIdx.x * blockDim.x + threadIdx.x;
  const int NX = 512 * 1024 / 4;   // 131072 float4s of x
  const int NH = 512 * 2048 / 4;   // 262144 float4s of h
  if (i < NX) {
    int b = i >> 8;                // 256 float4 per emb row
    int c = (i & 255) << 2;
    int row = idx[b];
    f32x4 v = *(const f32x4*)(emb + (size_t)row * 1024 + c);
    short4v o;
    #pragma unroll
    for (int j = 0; j < 4; ++j) o[j] = f2bf(v[j]);
    *(short4v*)(xbf + (size_t)b * 1024 + c) = o;
  } else if (i < NX + NH) {
    int j2 = i - NX;
    f32x4 v = *(const f32x4*)(hid + (size_t)j2 * 4);
    short4v o;
    #pragma unroll
    for (int j = 0; j < 4; ++j) o[j] = f2bf(v[j]);
    *(short4v*)(hbf + (size_t)j2 * 4) = o;
  }
}

__global__ void gates_kernel(const float* __restrict__ gi,
                             const float* __restrict__ gh,
                             const float* __restrict__ hid,
                             float* __restrict__ hnew,
                             short* __restrict__ hnbf)
{
  int i = blockIdx.x * blockDim.x + threadIdx.x;   // 512*512 threads, 4 cols each
  int b = i >> 9;
  int c = (i & 511) << 2;
  size_t gbase = (size_t)b * 6144 + c;
  f32x4 gir = *(const f32x4*)(gi + gbase);
  f32x4 giz = *(const f32x4*)(gi + gbase + 2048);
  f32x4 gin = *(const f32x4*)(gi + gbase + 4096);
  f32x4 ghr = *(const f32x4*)(gh + gbase);
  f32x4 ghz = *(const f32x4*)(gh + gbase + 2048);
  f32x4 ghn = *(const f32x4*)(gh + gbase + 4096);
  f32x4 hv  = *(const f32x4*)(hid + (size_t)b * 2048 + c);
  f32x4 hn;
  short4v hb;
  #pragma unroll
  for (int j = 0; j < 4; ++j) {
    float r = 1.f / (1.f + __expf(-(gir[j] + ghr[j])));
    float z = 1.f / (1.f + __expf(-(giz[j] + ghz[j])));
    float n = tanhf(gin[j] + r * ghn[j]);
    float o = (1.f - z) * n + z * hv[j];
    hn[j] = o;
    hb[j] = f2bf(o);
  }
  *(f32x4*)(hnew + (size_t)b * 2048 + c) = hn;
  *(short4v*)(hnbf + (size_t)b * 2048 + c) = hb;
}

extern "C" void kernel_launch(void* const* d_in, const int* in_sizes, int n_in,
                              void* d_out, int out_size, void* d_ws, size_t ws_size,
                              hipStream_t stream)
{
  const int*   idx   = (const int*)d_in[0];
  const float* hid   = (const float*)d_in[1];
  const float* emb   = (const float*)d_in[2];
  const float* W_ih  = (const float*)d_in[3];
  const float* W_hh  = (const float*)d_in[4];
  const float* b_ih  = (const float*)d_in[5];
  const float* b_hh  = (const float*)d_in[6];
  const float* fc_W  = (const float*)d_in[7];
  const float* fc_b  = (const float*)d_in[8];
  float* out = (float*)d_out;

  char* ws = (char*)d_ws;
  short* xbf  = (short*)(ws);                         // 512*1024 bf16 = 1 MB
  short* hbf  = (short*)(ws + 1048576);               // 512*2048 bf16 = 2 MB
  short* hnbf = (short*)(ws + 3145728);               // 512*2048 bf16 = 2 MB
  float* gi   = (float*)(ws + 5242880);               // 512*6144 f32 = 12.58 MB
  float* gh   = (float*)(ws + 17825792);              // 512*6144 f32 = 12.58 MB

  prep_kernel<<<1536, 256, 0, stream>>>(idx, hid, emb, xbf, hbf);
  gru_gemms_kernel<<<192, 512, 0, stream>>>(xbf, hbf, W_ih, W_hh, b_ih, b_hh, gi, gh);
  gates_kernel<<<1024, 256, 0, stream>>>(gi, gh, hid, out + (size_t)512 * 32000, hnbf);
  logits_kernel<<<500, 512, 0, stream>>>(hnbf, fc_W, fc_b, out);
}

// Round 8
// 196.298 us; speedup vs baseline: 2.8854x; 2.8854x over previous
//
#include <hip/hip_runtime.h>
#include <hip/hip_bf16.h>

typedef __attribute__((ext_vector_type(8))) short short8;
typedef __attribute__((ext_vector_type(4))) short short4v;
typedef __attribute__((ext_vector_type(4))) float f32x4;

__device__ __forceinline__ short f2bf(float f) {
  union { __hip_bfloat16 h; short s; } u;
  u.h = __float2bfloat16(f);
  return u.s;
}

// async 16B global->LDS DMA (m97/m103: width 16). LDS dst must be
// wave-uniform base + lane*16 (m104); global src is per-lane.
__device__ __forceinline__ void gll16(const void* g, void* l) {
  __builtin_amdgcn_global_load_lds(
      (const __attribute__((address_space(1))) void*)g,
      (__attribute__((address_space(3))) void*)l, 16, 0, 0);
}

#define SCHED_FENCE() __builtin_amdgcn_sched_barrier(0)

// C[512, N] = A_bf16[512, K] * W_f32[N, K]^T + bias.   BN = BF*16.
// 8 waves; wave w owns output rows [w*64, w*64+64), all share the W tile.
// Depth-3 DMA pipeline, BK=32 per iter. vmcnt queue holds ONLY DMA ops
// (A never passes through VGPRs) -> counted waits, never 0 in the loop.
// Swizzles are applied on the GLOBAL SOURCE address (DMA writes LDS
// linearly), inverse-applied on the LDS read:
//   A [512][32]bf16 rows 64B, 4 slots:  lds[r][s] = glob[r][s ^ ((r>>1)&3)]
//   W [BN][32]f32  rows 128B, 8 slots:  lds[r][s] = glob[r][s ^ (r&7)]
template<int BF>
__device__ __forceinline__ void gemm_dma(
    const short* __restrict__ A,
    const float* __restrict__ W,
    const float* __restrict__ bias,
    float* __restrict__ C,
    int K, int N, int n0, char* smem)
{
  constexpr int WOPS   = BF / 4;          // W DMA ops per thread per iter
  constexpr int WBYTES = BF * 16 * 128;   // W buffer bytes
  constexpr int ABYTES = 512 * 64;        // A buffer bytes (32 KB)
  constexpr int BUNDLE = 4 + WOPS;
  constexpr int WAIT   = 2 * BUNDLE;      // 2 bundles stay outstanding

  const int t   = threadIdx.x;
  const int w   = t >> 6;
  const int l   = t & 63;
  const int l16 = l & 15;
  const int lq  = l >> 4;

  f32x4 acc[4][BF];
  #pragma unroll
  for (int i = 0; i < 4; ++i)
    #pragma unroll
    for (int j = 0; j < BF; ++j) {
      f32x4 z = {0.f, 0.f, 0.f, 0.f};
      acc[i][j] = z;
    }

  // ---- DMA issue of one bundle (iter bi, k = bi*32) ----
  const int arow0  = w * 64 + (l >> 2);              // + j*16
  const int aslot  = (l & 3) ^ ((l >> 3) & 3);       // source slot (8 bf16)
  const int wslot  = (l & 7) ^ (l >> 3);             // source slot (4 f32)
  const int wrow0  = n0 + w * 8 + (l >> 3);          // + o*64

  auto issueBundle = [&](int bi) {
    const int buf = bi % 3;
    const int kb  = bi << 5;
    char* ab = smem + 3 * WBYTES + buf * ABYTES;
    char* wb = smem + buf * WBYTES;
    #pragma unroll
    for (int j = 0; j < 4; ++j)
      gll16(A + (size_t)(arow0 + j * 16) * K + kb + aslot * 8,
            ab + w * 4096 + j * 1024);
    #pragma unroll
    for (int o = 0; o < WOPS; ++o)
      gll16(W + (size_t)(wrow0 + o * 64) * K + kb + wslot * 4,
            wb + o * 8192 + w * 1024);
  };

  auto consume = [&](int bi) {
    const int buf = bi % 3;
    const char* ab = smem + 3 * WBYTES + buf * ABYTES;
    const char* wb = smem + buf * WBYTES;
    short8 a[4];
    const int asw = (lq ^ ((l16 >> 1) & 3)) * 16;
    #pragma unroll
    for (int mf = 0; mf < 4; ++mf)
      a[mf] = *(const short8*)(ab + (w * 64 + mf * 16 + l16) * 64 + asw);
    const int x = l16 & 7;
    #pragma unroll
    for (int nf = 0; nf < BF; ++nf) {
      const int row = nf * 16 + l16;
      f32x4 u = *(const f32x4*)(wb + row * 128 + ((2 * lq) ^ x) * 16);
      f32x4 v = *(const f32x4*)(wb + row * 128 + ((2 * lq + 1) ^ x) * 16);
      short8 b;
      #pragma unroll
      for (int i = 0; i < 4; ++i) { b[i] = f2bf(u[i]); b[i + 4] = f2bf(v[i]); }
      #pragma unroll
      for (int mf = 0; mf < 4; ++mf)
        acc[mf][nf] = __builtin_amdgcn_mfma_f32_16x16x32_bf16(a[mf], b, acc[mf][nf], 0, 0, 0);
    }
  };

  issueBundle(0); issueBundle(1); issueBundle(2);

  const int nt = K >> 5;
  for (int b = 0; b < nt - 3; ++b) {
    asm volatile("s_waitcnt vmcnt(%0)" :: "n"(WAIT) : "memory");
    SCHED_FENCE();
    __builtin_amdgcn_s_barrier();          // all waves' bundle-b DMA landed
    SCHED_FENCE();
    consume(b);
    asm volatile("s_waitcnt lgkmcnt(0)" ::: "memory");
    SCHED_FENCE();
    __builtin_amdgcn_s_barrier();          // all waves done reading buf b%3
    SCHED_FENCE();
    issueBundle(b + 3);                    // overwrite freed buffer
  }
  asm volatile("s_waitcnt vmcnt(0)" ::: "memory");
  SCHED_FENCE();
  __builtin_amdgcn_s_barrier();
  SCHED_FENCE();
  consume(nt - 3); consume(nt - 2); consume(nt - 1);
  __syncthreads();                          // before aliasing LDS for epilogue

  // ---- epilogue: LDS transpose -> full-line f32x4 stores ----
  constexpr int BN  = BF * 16;
  constexpr int EPS = BN + 4;               // f32 row stride (+4 skew)
  constexpr int CPR = BN / 4;               // f32x4 chunks per row
  float bvv[BF];
  #pragma unroll
  for (int nf = 0; nf < BF; ++nf) bvv[nf] = bias[n0 + nf * 16 + l16];

  float* ep = (float*)(smem) + w * 16 * EPS;
  const int erow = l / CPR;
  const int ecol = (l % CPR) * 4;
  #pragma unroll
  for (int mf = 0; mf < 4; ++mf) {
    #pragma unroll
    for (int nf = 0; nf < BF; ++nf)
      #pragma unroll
      for (int r = 0; r < 4; ++r)
        ep[(lq * 4 + r) * EPS + nf * 16 + l16] = acc[mf][nf][r] + bvv[nf];
    #pragma unroll
    for (int i = 0; i < BF; ++i) {
      const int row = i * (16 / BF) + erow;
      f32x4 vv = *(const f32x4*)&ep[row * EPS + ecol];
      *(f32x4*)&C[(size_t)(w * 64 + mf * 16 + row) * N + n0 + ecol] = vv;
    }
  }
}

__global__ __launch_bounds__(512, 2) void gru_gemms_kernel(
    const short* __restrict__ xbf, const short* __restrict__ hbf,
    const float* __restrict__ W_ih, const float* __restrict__ W_hh,
    const float* __restrict__ b_ih, const float* __restrict__ b_hh,
    float* __restrict__ gi, float* __restrict__ gh)
{
  __shared__ char smem[3 * (4 * 16 * 128) + 3 * 32768];   // 120 KB
  const bool second = blockIdx.x >= 96;
  const int nb = second ? (int)blockIdx.x - 96 : (int)blockIdx.x;
  gemm_dma<4>(second ? hbf : xbf,
              second ? W_hh : W_ih,
              second ? b_hh : b_ih,
              second ? gh : gi,
              second ? 2048 : 1024,
              6144, nb * 64, smem);
}

__global__ __launch_bounds__(512, 2) void logits_kernel(
    const short* __restrict__ hnbf, const float* __restrict__ fc_W,
    const float* __restrict__ fc_b, float* __restrict__ out)
{
  __shared__ char smem[3 * (8 * 16 * 128) + 3 * 32768];   // 144 KB
  gemm_dma<8>(hnbf, fc_W, fc_b, out, 2048, 32000, (int)blockIdx.x * 128, smem);
}

__global__ void prep_kernel(const int* __restrict__ idx,
                            const float* __restrict__ hid,
                            const float* __restrict__ emb,
                            short* __restrict__ xbf, short* __restrict__ hbf)
{
  int i = blockIdx.x * blockDim.x + threadIdx.x;
  const int NX = 512 * 1024 / 4;
  const int NH = 512 * 2048 / 4;
  if (i < NX) {
    int b = i >> 8;
    int c = (i & 255) << 2;
    int row = idx[b];
    f32x4 v = *(const f32x4*)(emb + (size_t)row * 1024 + c);
    short4v o;
    #pragma unroll
    for (int j = 0; j < 4; ++j) o[j] = f2bf(v[j]);
    *(short4v*)(xbf + (size_t)b * 1024 + c) = o;
  } else if (i < NX + NH) {
    int j2 = i - NX;
    f32x4 v = *(const f32x4*)(hid + (size_t)j2 * 4);
    short4v o;
    #pragma unroll
    for (int j = 0; j < 4; ++j) o[j] = f2bf(v[j]);
    *(short4v*)(hbf + (size_t)j2 * 4) = o;
  }
}

__global__ void gates_kernel(const float* __restrict__ gi,
                             const float* __restrict__ gh,
                             const float* __restrict__ hid,
                             float* __restrict__ hnew,
                             short* __restrict__ hnbf)
{
  int i = blockIdx.x * blockDim.x + threadIdx.x;
  int b = i >> 9;
  int c = (i & 511) << 2;
  size_t gbase = (size_t)b * 6144 + c;
  f32x4 gir = *(const f32x4*)(gi + gbase);
  f32x4 giz = *(const f32x4*)(gi + gbase + 2048);
  f32x4 gin = *(const f32x4*)(gi + gbase + 4096);
  f32x4 ghr = *(const f32x4*)(gh + gbase);
  f32x4 ghz = *(const f32x4*)(gh + gbase + 2048);
  f32x4 ghn = *(const f32x4*)(gh + gbase + 4096);
  f32x4 hv  = *(const f32x4*)(hid + (size_t)b * 2048 + c);
  f32x4 hn;
  short4v hb;
  #pragma unroll
  for (int j = 0; j < 4; ++j) {
    float r = 1.f / (1.f + __expf(-(gir[j] + ghr[j])));
    float z = 1.f / (1.f + __expf(-(giz[j] + ghz[j])));
    float n = tanhf(gin[j] + r * ghn[j]);
    float o = (1.f - z) * n + z * hv[j];
    hn[j] = o;
    hb[j] = f2bf(o);
  }
  *(f32x4*)(hnew + (size_t)b * 2048 + c) = hn;
  *(short4v*)(hnbf + (size_t)b * 2048 + c) = hb;
}

extern "C" void kernel_launch(void* const* d_in, const int* in_sizes, int n_in,
                              void* d_out, int out_size, void* d_ws, size_t ws_size,
                              hipStream_t stream)
{
  const int*   idx   = (const int*)d_in[0];
  const float* hid   = (const float*)d_in[1];
  const float* emb   = (const float*)d_in[2];
  const float* W_ih  = (const float*)d_in[3];
  const float* W_hh  = (const float*)d_in[4];
  const float* b_ih  = (const float*)d_in[5];
  const float* b_hh  = (const float*)d_in[6];
  const float* fc_W  = (const float*)d_in[7];
  const float* fc_b  = (const float*)d_in[8];
  float* out = (float*)d_out;

  char* ws = (char*)d_ws;
  short* xbf  = (short*)(ws);
  short* hbf  = (short*)(ws + 1048576);
  short* hnbf = (short*)(ws + 3145728);
  float* gi   = (float*)(ws + 5242880);
  float* gh   = (float*)(ws + 17825792);

  prep_kernel<<<1536, 256, 0, stream>>>(idx, hid, emb, xbf, hbf);
  gru_gemms_kernel<<<192, 512, 0, stream>>>(xbf, hbf, W_ih, W_hh, b_ih, b_hh, gi, gh);
  gates_kernel<<<1024, 256, 0, stream>>>(gi, gh, hid, out + (size_t)512 * 32000, hnbf);
  // N=32000 / BN=128 = 250 blocks, 1 block/CU, single pass, W read once
  logits_kernel<<<250, 512, 0, stream>>>(hnbf, fc_W, fc_b, out);
}